// Round 15
// baseline (753.604 us; speedup 1.0000x reference)
//
#include <hip/hip_runtime.h>
#include <hip/hip_bf16.h>

#define DEVFN __device__ __forceinline__

typedef __attribute__((ext_vector_type(8))) short short8v;
typedef __attribute__((ext_vector_type(4))) float f32x4;

constexpr int NN = 50000;   // nodes
constexpr int NE = 600000;  // edges
constexpr int NG = 256;     // graphs
constexpr int FN = 92;      // node feat
constexpr int FE = 50;      // edge feat
constexpr int H  = 128;     // hidden
constexpr int NL = 3;       // layers
constexpr int TE = 128;     // edges per block in MFMA edge kernel
constexpr int NBLK_E = (NE + TE - 1) / TE;

// ---------- bf16 helpers ----------
DEVFN ushort f2bf(float x) {
    unsigned u = __float_as_uint(x);
    unsigned r = (u + 0x7fffu + ((u >> 16) & 1u)) >> 16;   // RNE
    return (ushort)r;
}
DEVFN float bftof(ushort u) { return __uint_as_float(((unsigned)u) << 16); }
DEVFN float bflo(unsigned w) { return __uint_as_float(w << 16); }
DEVFN float bfhi(unsigned w) { return __uint_as_float(w & 0xffff0000u); }

// ---------- CSR build ----------
__global__ void k_deg(const int* __restrict__ dst, int* __restrict__ deg)
{
    const int e = blockIdx.x * 256 + threadIdx.x;
    if (e < NE) atomicAdd(&deg[dst[e]], 1);
}

// exclusive scan over deg -> start[NN+1]; also emits dis = rsqrt(deg+1)
__global__ void k_scan(const int* __restrict__ deg, int* __restrict__ start,
                       float* __restrict__ dis)
{
    constexpr int T = 1024;
    __shared__ int partial[T];
    const int tid = threadIdx.x;
    const int chunk = (NN + T - 1) / T;
    const int base = tid * chunk;
    int sum = 0;
    for (int i = 0; i < chunk; i++) {
        const int idx = base + i;
        if (idx < NN) sum += deg[idx];
    }
    partial[tid] = sum;
    __syncthreads();
    for (int off = 1; off < T; off <<= 1) {
        const int v = (tid >= off) ? partial[tid - off] : 0;
        __syncthreads();
        partial[tid] += v;
        __syncthreads();
    }
    int run = (tid == 0) ? 0 : partial[tid - 1];
    for (int i = 0; i < chunk; i++) {
        const int idx = base + i;
        if (idx < NN) {
            const int d = deg[idx];
            start[idx] = run; run += d;
            dis[idx] = rsqrtf((float)d + 1.0f);
        }
    }
    if (tid == T - 1) start[NN] = run;
}

__global__ void k_place(const int* __restrict__ dst, const int* __restrict__ start,
                        int* __restrict__ cursor, int* __restrict__ perm)
{
    const int e = blockIdx.x * 256 + threadIdx.x;
    if (e < NE) {
        const int d = dst[e];
        const int r = atomicAdd(&cursor[d], 1);
        perm[start[d] + r] = e;
    }
}

// deterministic per-node sort (by edge id) done in LDS; emits pairs directly
__global__ void k_sortseg(const int* __restrict__ start, int* __restrict__ perm,
                          const int* __restrict__ src, int2* __restrict__ pairs)
{
    __shared__ int seg[256][33];   // +1 pad vs bank conflicts
    const int n = blockIdx.x * 256 + threadIdx.x;
    if (n >= NN) return;
    const int s0 = start[n], s1 = start[n + 1];
    const int d = s1 - s0;
    if (d <= 32) {
        int* a = seg[threadIdx.x];
        for (int i = 0; i < d; i++) a[i] = perm[s0 + i];
        for (int i = 1; i < d; i++) {
            const int v = a[i];
            int j = i - 1;
            while (j >= 0 && a[j] > v) { a[j + 1] = a[j]; j--; }
            a[j + 1] = v;
        }
        for (int i = 0; i < d; i++) {
            const int eid = a[i];
            pairs[s0 + i] = make_int2(eid, src[eid]);
        }
    } else {
        for (int i = s0 + 1; i < s1; i++) {
            const int v = perm[i];
            int j = i - 1;
            while (j >= s0 && perm[j] > v) { perm[j + 1] = perm[j]; j--; }
            perm[j + 1] = v;
        }
        for (int i = s0; i < s1; i++) {
            const int eid = perm[i];
            pairs[i] = make_int2(eid, src[eid]);
        }
    }
}

// ---------- single-launch weight pack ----------
// per-matrix layout: idx = (((ct*KC+kc)*nsp+sp)*64 + lane)*8 + j
// value = part_sp(W[k][m]), k = kc*32+(lane>>4)*8+j (0 if k>=K), m = ct*16+(lane&15)
DEVFN void packone(const float* __restrict__ W, int K, int KC, int nsp,
                   int idx, ushort* __restrict__ out)
{
    const int j = idx & 7, lane = (idx >> 3) & 63;
    const int sp = (idx >> 9) % nsp;
    const int rest = (idx >> 9) / nsp;
    const int kc = rest % KC;
    const int ct = rest / KC;
    const int k = kc * 32 + (lane >> 4) * 8 + j;
    const int m = ct * 16 + (lane & 15);
    const float w = (k < K) ? W[(size_t)k * H + m] : 0.f;
    const ushort hh = f2bf(w);
    out[idx] = (sp == 0) ? hh : f2bf(w - bftof(hh));
}

constexpr int SZ_W1 = 8 * 2 * 512;           // plain, KC=2
constexpr int SZ_W2 = 8 * 4 * 512;           // plain, KC=4
constexpr int SZ_WN = 8 * 3 * 2 * 512;       // split, KC=3
constexpr int SZ_WC = 8 * 4 * 2 * 512;       // split, KC=4 (per layer)

__global__ void k_packall(const float* __restrict__ We1, const float* __restrict__ We2,
                          const float* __restrict__ Wn, const float* __restrict__ Wc,
                          ushort* __restrict__ w1p, ushort* __restrict__ w2p,
                          ushort* __restrict__ wnp, ushort* __restrict__ wcp)
{
    int idx = blockIdx.x * 256 + threadIdx.x;
    if (idx < SZ_W1) { packone(We1, FE, 2, 1, idx, w1p); return; }
    idx -= SZ_W1;
    if (idx < SZ_W2) { packone(We2, H, 4, 1, idx, w2p); return; }
    idx -= SZ_W2;
    if (idx < SZ_WN) { packone(Wn, FN, 3, 2, idx, wnp); return; }
    idx -= SZ_WN;
    if (idx < 3 * SZ_WC) {
        const int l = idx / SZ_WC;
        packone(Wc + (size_t)l * H * H, H, 4, 2, idx - l * SZ_WC, wcp + (size_t)l * SZ_WC);
    }
}
constexpr int PACK_TOT = SZ_W1 + SZ_W2 + SZ_WN + 3 * SZ_WC;

// ---------- node embedding: h = x @ Wn + bn (split x split, ~exact), bf16 out ----------
__global__ __launch_bounds__(256, 4) void k_node_embed(
    const float* __restrict__ X, const ushort* __restrict__ wp,
    const float* __restrict__ bias, ushort* __restrict__ hb, int nrows)
{
    constexpr int KC = 3, K = FN, WV = 48;   // 4B words staged per row
    __shared__ unsigned hi_s[64 * 64];   // 16KB: [row][256B], swizzled
    __shared__ unsigned lo_s[64 * 64];   // 16KB
    const int tid = threadIdx.x;
    const int r0 = blockIdx.x * 64;

    for (int i = tid; i < 64 * WV; i += 256) {
        const int row = i / WV, w = i - row * WV;
        const int gr = min(r0 + row, nrows - 1);
        const int k = w * 2;
        unsigned hw = 0, lw = 0;
        if (k < K) {
            const float vx = X[(size_t)gr * K + k];
            const float vy = (k + 1 < K) ? X[(size_t)gr * K + k + 1] : 0.f;
            const ushort hx = f2bf(vx), hy = f2bf(vy);
            hw = (unsigned)hx | ((unsigned)hy << 16);
            lw = (unsigned)f2bf(vx - bftof(hx)) | ((unsigned)f2bf(vy - bftof(hy)) << 16);
        }
        const int a = (row * 256 + ((w * 4) ^ ((row & 7) << 4))) >> 2;
        hi_s[a] = hw; lo_s[a] = lw;
    }
    __syncthreads();

    const int wid = tid >> 6, lane = tid & 63;
    const int q = lane >> 4, e = lane & 15;
    const int row = wid * 16 + e;
    const short8v* wf = (const short8v*)wp;

    f32x4 acc[8];
#pragma unroll
    for (int ct = 0; ct < 8; ct++) acc[ct] = (f32x4)0.f;

#pragma unroll
    for (int kc = 0; kc < KC; kc++) {
        const int off = row * 256 + ((kc * 64 + q * 16) ^ ((row & 7) << 4));
        const short8v bh = *(const short8v*)((const char*)hi_s + off);
        const short8v bl = *(const short8v*)((const char*)lo_s + off);
#pragma unroll
        for (int ct = 0; ct < 8; ct++) {
            const short8v a_h = wf[((ct * KC + kc) * 2 + 0) * 64 + lane];
            const short8v a_l = wf[((ct * KC + kc) * 2 + 1) * 64 + lane];
            acc[ct] = __builtin_amdgcn_mfma_f32_16x16x32_bf16(a_h, bh, acc[ct], 0, 0, 0);
            acc[ct] = __builtin_amdgcn_mfma_f32_16x16x32_bf16(a_h, bl, acc[ct], 0, 0, 0);
            acc[ct] = __builtin_amdgcn_mfma_f32_16x16x32_bf16(a_l, bh, acc[ct], 0, 0, 0);
        }
    }

    const int node = r0 + row;
    if (node < nrows) {
#pragma unroll
        for (int ct = 0; ct < 8; ct++) {
            const int col = ct * 16 + q * 4;
            const float4 bb = *(const float4*)&bias[col];
            ushort4 ub;
            ub.x = f2bf(acc[ct][0] + bb.x);
            ub.y = f2bf(acc[ct][1] + bb.y);
            ub.z = f2bf(acc[ct][2] + bb.z);
            ub.w = f2bf(acc[ct][3] + bb.w);
            *(ushort4*)&hb[(size_t)node * H + col] = ub;
        }
    }
}

// ---------- layer transform: t = h @ Wc (split-W x bf16-h, 2-term), bf16 out ----------
__global__ __launch_bounds__(256, 4) void k_node_xform(
    const ushort* __restrict__ hb, const ushort* __restrict__ wp,
    ushort* __restrict__ tb, int nrows)
{
    __shared__ unsigned b_s[64 * 64];   // 16KB: [row][256B], swizzled
    const int tid = threadIdx.x;
    const int r0 = blockIdx.x * 64;

    for (int i = tid; i < 64 * 64; i += 256) {
        const int row = i >> 6, w = i & 63;
        const int gr = min(r0 + row, nrows - 1);
        const unsigned hw = ((const unsigned*)&hb[(size_t)gr * H])[w];
        b_s[(row * 256 + ((w * 4) ^ ((row & 7) << 4))) >> 2] = hw;
    }
    __syncthreads();

    const int wid = tid >> 6, lane = tid & 63;
    const int q = lane >> 4, e = lane & 15;
    const int row = wid * 16 + e;
    const short8v* wf = (const short8v*)wp;

    f32x4 acc[8];
#pragma unroll
    for (int ct = 0; ct < 8; ct++) acc[ct] = (f32x4)0.f;

#pragma unroll
    for (int kc = 0; kc < 4; kc++) {
        const int off = row * 256 + ((kc * 64 + q * 16) ^ ((row & 7) << 4));
        const short8v b = *(const short8v*)((const char*)b_s + off);
#pragma unroll
        for (int ct = 0; ct < 8; ct++) {
            const short8v a_h = wf[((ct * 4 + kc) * 2 + 0) * 64 + lane];
            const short8v a_l = wf[((ct * 4 + kc) * 2 + 1) * 64 + lane];
            acc[ct] = __builtin_amdgcn_mfma_f32_16x16x32_bf16(a_h, b, acc[ct], 0, 0, 0);
            acc[ct] = __builtin_amdgcn_mfma_f32_16x16x32_bf16(a_l, b, acc[ct], 0, 0, 0);
        }
    }

    const int node = r0 + row;
    if (node < nrows) {
#pragma unroll
        for (int ct = 0; ct < 8; ct++) {
            const int col = ct * 16 + q * 4;
            ushort4 ub;
            ub.x = f2bf(acc[ct][0]);
            ub.y = f2bf(acc[ct][1]);
            ub.z = f2bf(acc[ct][2]);
            ub.w = f2bf(acc[ct][3]);
            *(ushort4*)&tb[(size_t)node * H + col] = ub;
        }
    }
}

// ---------- MFMA edge MLP: original order, plain-bf16 weights, nt-stores ----------
__global__ __launch_bounds__(256, 4) void k_edge_mfma(
    const float* __restrict__ attr, const int* __restrict__ src,
    const int* __restrict__ dst, const float* __restrict__ dis,
    const ushort* __restrict__ w1p, const ushort* __restrict__ w2p,
    const float* __restrict__ b1, const float* __restrict__ b2,
    ushort* __restrict__ eout)
{
    __shared__ unsigned ah_s[TE * 32];    // attr bf16 [row][128B], swizzled, 16KB
    __shared__ unsigned tmp_s[TE * 32];   // tmp  bf16 [row][128B], swizzled, 16KB
    __shared__ float nrm_s[TE];
    const int tid = threadIdx.x;
    const int e0 = blockIdx.x * TE;

    if (tid < TE) {
        const int ee = min(e0 + tid, NE - 1);
        nrm_s[tid] = dis[src[ee]] * dis[dst[ee]];
    }
    for (int i = tid; i < TE * 32; i += 256) {
        const int row = i >> 5, w = i & 31;
        unsigned hw = 0;
        if (w < 25) {
            const int ee = min(e0 + row, NE - 1);
            const float2 v = *(const float2*)&attr[(size_t)ee * FE + w * 2];
            hw = (unsigned)f2bf(v.x) | ((unsigned)f2bf(v.y) << 16);
        }
        ah_s[(row * 128 + ((w * 4) ^ ((row & 7) << 4))) >> 2] = hw;
    }
    __syncthreads();

    const int wid = tid >> 6, lane = tid & 63;
    const int q = lane >> 4, e = lane & 15;
    const int rowA = (wid * 2 + 0) * 16 + e;
    const int rowB = (wid * 2 + 1) * 16 + e;
    const short8v* w1f = (const short8v*)w1p;
    const short8v* w2f = (const short8v*)w2p;

    f32x4 acc2[8][2];
#pragma unroll
    for (int ct = 0; ct < 8; ct++)
#pragma unroll
        for (int et = 0; et < 2; et++) acc2[ct][et] = (f32x4)0.f;

#pragma unroll
    for (int p = 0; p < 2; p++) {
        // ---- GEMM1: tmp cols [p*64, p*64+64) ----
        f32x4 acc1[4][2];
#pragma unroll
        for (int c = 0; c < 4; c++)
#pragma unroll
            for (int et = 0; et < 2; et++) acc1[c][et] = (f32x4)0.f;

#pragma unroll
        for (int kc = 0; kc < 2; kc++) {
            const short8v bA = *(const short8v*)((const char*)ah_s +
                rowA * 128 + ((kc * 64 + q * 16) ^ ((rowA & 7) << 4)));
            const short8v bB = *(const short8v*)((const char*)ah_s +
                rowB * 128 + ((kc * 64 + q * 16) ^ ((rowB & 7) << 4)));
            short8v a1r[4];
#pragma unroll
            for (int c = 0; c < 4; c++)
                a1r[c] = w1f[((p * 4 + c) * 2 + kc) * 64 + lane];
#pragma unroll
            for (int c = 0; c < 4; c++) {
                acc1[c][0] = __builtin_amdgcn_mfma_f32_16x16x32_bf16(a1r[c], bA, acc1[c][0], 0, 0, 0);
                acc1[c][1] = __builtin_amdgcn_mfma_f32_16x16x32_bf16(a1r[c], bB, acc1[c][1], 0, 0, 0);
            }
        }

        if (p == 1) __syncthreads();   // all GEMM2(p=0) tmp reads done before overwrite

        // ---- bias + relu + bf16 pack -> tmp LDS ----
#pragma unroll
        for (int c = 0; c < 4; c++) {
            const int ct = p * 4 + c;
            const float4 b1v = *(const float4*)&b1[ct * 16 + q * 4];
#pragma unroll
            for (int et = 0; et < 2; et++) {
                const int row = (wid * 2 + et) * 16 + e;
                const float v0 = fmaxf(acc1[c][et][0] + b1v.x, 0.f);
                const float v1 = fmaxf(acc1[c][et][1] + b1v.y, 0.f);
                const float v2 = fmaxf(acc1[c][et][2] + b1v.z, 0.f);
                const float v3 = fmaxf(acc1[c][et][3] + b1v.w, 0.f);
                unsigned* dptr = &tmp_s[(row * 128 + ((c * 32 + q * 8) ^ ((row & 7) << 4))) >> 2];
                dptr[0] = (unsigned)f2bf(v0) | ((unsigned)f2bf(v1) << 16);
                dptr[1] = (unsigned)f2bf(v2) | ((unsigned)f2bf(v3) << 16);
            }
        }
        __syncthreads();

        // ---- GEMM2: kc2 = 2p, 2p+1 ----
#pragma unroll
        for (int kk = 0; kk < 2; kk++) {
            const int kc2 = p * 2 + kk;
            const short8v tA = *(const short8v*)((const char*)tmp_s +
                rowA * 128 + ((kk * 64 + q * 16) ^ ((rowA & 7) << 4)));
            const short8v tB = *(const short8v*)((const char*)tmp_s +
                rowB * 128 + ((kk * 64 + q * 16) ^ ((rowB & 7) << 4)));
            short8v a2r[8];
#pragma unroll
            for (int ct2 = 0; ct2 < 8; ct2++)
                a2r[ct2] = w2f[(ct2 * 4 + kc2) * 64 + lane];
#pragma unroll
            for (int ct2 = 0; ct2 < 8; ct2++) {
                acc2[ct2][0] = __builtin_amdgcn_mfma_f32_16x16x32_bf16(a2r[ct2], tA, acc2[ct2][0], 0, 0, 0);
                acc2[ct2][1] = __builtin_amdgcn_mfma_f32_16x16x32_bf16(a2r[ct2], tB, acc2[ct2][1], 0, 0, 0);
            }
        }
    }

    // ---- epilogue: (acc2+b2)*nrm -> bf16, nontemporal sequential stores ----
#pragma unroll
    for (int ct2 = 0; ct2 < 8; ct2++) {
        const float4 b2v = *(const float4*)&b2[ct2 * 16 + q * 4];
#pragma unroll
        for (int et = 0; et < 2; et++) {
            const int row = (wid * 2 + et) * 16 + e;
            const int ee = e0 + row;
            if (ee < NE) {
                const float nm = nrm_s[row];
                const unsigned u0 = (unsigned)f2bf((acc2[ct2][et][0] + b2v.x) * nm) |
                                    ((unsigned)f2bf((acc2[ct2][et][1] + b2v.y) * nm) << 16);
                const unsigned u1 = (unsigned)f2bf((acc2[ct2][et][2] + b2v.z) * nm) |
                                    ((unsigned)f2bf((acc2[ct2][et][3] + b2v.w) * nm) << 16);
                const unsigned long long u = (unsigned long long)u0 |
                                             ((unsigned long long)u1 << 32);
                __builtin_nontemporal_store(u,
                    (unsigned long long*)&eout[(size_t)ee * H + ct2 * 16 + q * 4]);
            }
        }
    }
}

// ---------- CSR aggregate + self-loop + bias + relu, fused; bf16 h out ----------
// 4 nodes per wave, 16 lanes per node; 2 slots/iter, pairs look-ahead (R13 form)
__global__ void k_agg(const ushort* __restrict__ tbf, const ushort* __restrict__ ebuf,
                      const int2* __restrict__ pairs, const int* __restrict__ start,
                      const float* __restrict__ dis, const float* __restrict__ bias,
                      ushort* __restrict__ hb)
{
    const int wv = (blockIdx.x * blockDim.x + threadIdx.x) >> 6;
    const int lane = threadIdx.x & 63;
    const int node = wv * 4 + (lane >> 4);
    if (node >= NN) return;
    const int f0 = (lane & 15) * 8;
    const int s0 = start[node], s1 = start[node + 1];

    float a0[8], a1[8];
#pragma unroll
    for (int i = 0; i < 8; i++) { a0[i] = 0.f; a1[i] = 0.f; }

    int slot = s0;
    int2 pA = pairs[min(slot, NE - 1)];
    int2 pB = pairs[min(slot + 1, NE - 1)];
    for (; slot + 2 <= s1; ) {
        const int2 cA = pA, cB = pB;
        pA = pairs[min(slot + 2, NE - 1)];
        pB = pairs[min(slot + 3, NE - 1)];
        const uint4 eA = *(const uint4*)&ebuf[(size_t)cA.x * H + f0];
        const uint4 tA = *(const uint4*)&tbf[(size_t)cA.y * H + f0];
        const uint4 eB = *(const uint4*)&ebuf[(size_t)cB.x * H + f0];
        const uint4 tB = *(const uint4*)&tbf[(size_t)cB.y * H + f0];
        const unsigned ea[4] = {eA.x, eA.y, eA.z, eA.w};
        const unsigned ta[4] = {tA.x, tA.y, tA.z, tA.w};
        const unsigned eb[4] = {eB.x, eB.y, eB.z, eB.w};
        const unsigned tb[4] = {tB.x, tB.y, tB.z, tB.w};
#pragma unroll
        for (int w = 0; w < 4; w++) {
            a0[2 * w]     = fmaf(bflo(ta[w]), bflo(ea[w]), a0[2 * w]);
            a0[2 * w + 1] = fmaf(bfhi(ta[w]), bfhi(ea[w]), a0[2 * w + 1]);
            a1[2 * w]     = fmaf(bflo(tb[w]), bflo(eb[w]), a1[2 * w]);
            a1[2 * w + 1] = fmaf(bfhi(tb[w]), bfhi(eb[w]), a1[2 * w + 1]);
        }
        slot += 2;
    }
    if (slot < s1) {
        const uint4 eA = *(const uint4*)&ebuf[(size_t)pA.x * H + f0];
        const uint4 tA = *(const uint4*)&tbf[(size_t)pA.y * H + f0];
        const unsigned ea[4] = {eA.x, eA.y, eA.z, eA.w};
        const unsigned ta[4] = {tA.x, tA.y, tA.z, tA.w};
#pragma unroll
        for (int w = 0; w < 4; w++) {
            a0[2 * w]     = fmaf(bflo(ta[w]), bflo(ea[w]), a0[2 * w]);
            a0[2 * w + 1] = fmaf(bfhi(ta[w]), bfhi(ea[w]), a0[2 * w + 1]);
        }
    }

    const float ds = dis[node];
    const float d2 = ds * ds;
    const uint4 tsv = *(const uint4*)&tbf[(size_t)node * H + f0];
    const unsigned ts[4] = {tsv.x, tsv.y, tsv.z, tsv.w};
    const float4 bb0 = *(const float4*)&bias[f0];
    const float4 bb1 = *(const float4*)&bias[f0 + 4];
    const float bb[8] = {bb0.x, bb0.y, bb0.z, bb0.w, bb1.x, bb1.y, bb1.z, bb1.w};
    ushort r[8];
#pragma unroll
    for (int w = 0; w < 4; w++) {
        r[2 * w]     = f2bf(fmaxf(a0[2 * w]     + a1[2 * w]     + bflo(ts[w]) * d2 + bb[2 * w],     0.f));
        r[2 * w + 1] = f2bf(fmaxf(a0[2 * w + 1] + a1[2 * w + 1] + bfhi(ts[w]) * d2 + bb[2 * w + 1], 0.f));
    }
    ushort4 o0 = {r[0], r[1], r[2], r[3]};
    ushort4 o1 = {r[4], r[5], r[6], r[7]};
    *(ushort4*)&hb[(size_t)node * H + f0]     = o0;
    *(ushort4*)&hb[(size_t)node * H + f0 + 4] = o1;
}

// ---------- fused mean-pool + head (bf16 h input, inline graph bounds) ----------
DEVFN int lbound(const int* __restrict__ batch, int g)
{
    int lo = 0, hi = NN;
    while (lo < hi) {
        const int mid = (lo + hi) >> 1;
        if (batch[mid] < g) lo = mid + 1; else hi = mid;
    }
    return lo;
}

__global__ void k_pool_head(const ushort* __restrict__ hb, const int* __restrict__ batch,
                            const float* __restrict__ W1, const float* __restrict__ b1,
                            const float* __restrict__ W2, const float* __restrict__ b2,
                            float* __restrict__ out)
{
    __shared__ float gs[H];
    __shared__ float red[2];
    const int gi = blockIdx.x;
    const int f = threadIdx.x;
    const int n0 = lbound(batch, gi);
    const int n1 = lbound(batch, gi + 1);
    float sum = 0.f;
    for (int n = n0; n < n1; n++) sum += bftof(hb[(size_t)n * H + f]);
    const float cnt = fmaxf((float)(n1 - n0), 1.0f);
    gs[f] = sum / cnt;
    __syncthreads();
    float acc = b1[f];
#pragma unroll 4
    for (int k = 0; k < H; k++) acc = fmaf(gs[k], W1[k * H + f], acc);
    float v = fmaxf(acc, 0.f) * W2[f];
#pragma unroll
    for (int off = 32; off > 0; off >>= 1) v += __shfl_down(v, off, 64);
    if ((f & 63) == 0) red[f >> 6] = v;
    __syncthreads();
    if (f == 0) out[gi] = red[0] + red[1] + b2[0];
}

extern "C" void kernel_launch(void* const* d_in, const int* in_sizes, int n_in,
                              void* d_out, int out_size, void* d_ws, size_t ws_size,
                              hipStream_t stream)
{
    const float* x    = (const float*)d_in[0];
    const float* attr = (const float*)d_in[1];
    const int*   ei   = (const int*)d_in[2];
    const int*   bat  = (const int*)d_in[3];
    const float* Wn   = (const float*)d_in[4];
    const float* bn   = (const float*)d_in[5];
    const float* We1  = (const float*)d_in[6];
    const float* be1  = (const float*)d_in[7];
    const float* We2  = (const float*)d_in[8];
    const float* be2  = (const float*)d_in[9];
    const float* Wc   = (const float*)d_in[10];
    const float* bc   = (const float*)d_in[11];
    const float* Wl1  = (const float*)d_in[12];
    const float* bl1  = (const float*)d_in[13];
    const float* Wl2  = (const float*)d_in[14];
    const float* bl2  = (const float*)d_in[15];
    float* out = (float*)d_out;
    const int* src = ei;
    const int* dst = ei + NE;

    auto aln = [](size_t v) { return (v + 255) & ~(size_t)255; };
    char* p = (char*)d_ws;
    auto carve = [&](size_t bytes) { char* r = p; p += aln(bytes); return r; };
    ushort* hb      = (ushort*)carve((size_t)NN * H * 2);
    ushort* tbf     = (ushort*)carve((size_t)NN * H * 2);
    int*    deg     = (int*)  carve((size_t)NN * 4);
    int*    startC  = (int*)  carve((size_t)(NN + 1) * 4);
    int*    cursor  = (int*)  carve((size_t)NN * 4);
    float*  dis     = (float*)carve((size_t)NN * 4);
    int*    perm    = (int*)  carve((size_t)NE * 4);
    int2*   pairs   = (int2*) carve((size_t)NE * 8);
    ushort* w1p     = (ushort*)carve((size_t)SZ_W1 * 2);
    ushort* w2p     = (ushort*)carve((size_t)SZ_W2 * 2);
    ushort* wnp     = (ushort*)carve((size_t)SZ_WN * 2);
    ushort* wcp     = (ushort*)carve((size_t)3 * SZ_WC * 2);
    ushort* ebuf    = (ushort*)carve((size_t)NE * H * 2);

    // CSR build (deterministic); single memset covers deg..cursor span
    const size_t zspan = (size_t)((char*)cursor - (char*)deg) + (size_t)NN * 4;
    hipMemsetAsync(deg, 0, zspan, stream);
    k_deg<<<(NE + 255) / 256, 256, 0, stream>>>(dst, deg);
    k_scan<<<1, 1024, 0, stream>>>(deg, startC, dis);
    k_place<<<(NE + 255) / 256, 256, 0, stream>>>(dst, startC, cursor, perm);
    k_sortseg<<<(NN + 255) / 256, 256, 0, stream>>>(startC, perm, src, pairs);

    // all weight packing in one launch
    k_packall<<<(PACK_TOT + 255) / 256, 256, 0, stream>>>(We1, We2, Wn, Wc,
                                                          w1p, w2p, wnp, wcp);

    // node embedding (split x split, ~exact), bf16 h out
    k_node_embed<<<(NN + 63) / 64, 256, 0, stream>>>(x, wnp, bn, hb, NN);

    // edge MLP (MFMA, original order, nt sequential store, norm folded)
    k_edge_mfma<<<NBLK_E, 256, 0, stream>>>(attr, src, dst, dis,
                                            w1p, w2p, be1, be2, ebuf);

    // GCN layers
    for (int l = 0; l < NL; l++) {
        k_node_xform<<<(NN + 63) / 64, 256, 0, stream>>>(
            hb, wcp + (size_t)l * SZ_WC, tbf, NN);
        k_agg<<<((NN + 3) / 4 * 64 + 255) / 256, 256, 0, stream>>>(
            tbf, ebuf, pairs, startC, dis, bc + (size_t)l * H, hb);
    }

    // fused pool + head (inline bounds)
    k_pool_head<<<NG, H, 0, stream>>>(hb, bat, Wl1, bl1, Wl2, bl2, out);
}

// Round 16
// 704.121 us; speedup vs baseline: 1.0703x; 1.0703x over previous
//
#include <hip/hip_runtime.h>
#include <hip/hip_bf16.h>

#define DEVFN __device__ __forceinline__

typedef __attribute__((ext_vector_type(8))) short short8v;
typedef __attribute__((ext_vector_type(4))) float f32x4;

constexpr int NN = 50000;   // nodes
constexpr int NE = 600000;  // edges
constexpr int NG = 256;     // graphs
constexpr int FN = 92;      // node feat
constexpr int FE = 50;      // edge feat
constexpr int H  = 128;     // hidden
constexpr int NL = 3;       // layers
constexpr int TE = 128;     // edges per block in MFMA edge kernel
constexpr int NBLK_E = (NE + TE - 1) / TE;

// ---------- bf16 helpers ----------
DEVFN ushort f2bf(float x) {
    unsigned u = __float_as_uint(x);
    unsigned r = (u + 0x7fffu + ((u >> 16) & 1u)) >> 16;   // RNE
    return (ushort)r;
}
DEVFN float bftof(ushort u) { return __uint_as_float(((unsigned)u) << 16); }
DEVFN float bflo(unsigned w) { return __uint_as_float(w << 16); }
DEVFN float bfhi(unsigned w) { return __uint_as_float(w & 0xffff0000u); }

// ---------- CSR build ----------
__global__ void k_deg(const int* __restrict__ dst, int* __restrict__ deg)
{
    const int e = blockIdx.x * 256 + threadIdx.x;
    if (e < NE) atomicAdd(&deg[dst[e]], 1);
}

// exclusive scan over deg -> start[NN+1]; also emits dis = rsqrt(deg+1)
__global__ void k_scan(const int* __restrict__ deg, int* __restrict__ start,
                       float* __restrict__ dis)
{
    constexpr int T = 1024;
    __shared__ int partial[T];
    const int tid = threadIdx.x;
    const int chunk = (NN + T - 1) / T;
    const int base = tid * chunk;
    int sum = 0;
    for (int i = 0; i < chunk; i++) {
        const int idx = base + i;
        if (idx < NN) sum += deg[idx];
    }
    partial[tid] = sum;
    __syncthreads();
    for (int off = 1; off < T; off <<= 1) {
        const int v = (tid >= off) ? partial[tid - off] : 0;
        __syncthreads();
        partial[tid] += v;
        __syncthreads();
    }
    int run = (tid == 0) ? 0 : partial[tid - 1];
    for (int i = 0; i < chunk; i++) {
        const int idx = base + i;
        if (idx < NN) {
            const int d = deg[idx];
            start[idx] = run; run += d;
            dis[idx] = rsqrtf((float)d + 1.0f);
        }
    }
    if (tid == T - 1) start[NN] = run;
}

__global__ void k_place(const int* __restrict__ dst, const int* __restrict__ start,
                        int* __restrict__ cursor, int* __restrict__ perm)
{
    const int e = blockIdx.x * 256 + threadIdx.x;
    if (e < NE) {
        const int d = dst[e];
        const int r = atomicAdd(&cursor[d], 1);
        perm[start[d] + r] = e;
    }
}

// deterministic per-node sort (by edge id) done in LDS; emits pairs directly
__global__ void k_sortseg(const int* __restrict__ start, int* __restrict__ perm,
                          const int* __restrict__ src, int2* __restrict__ pairs)
{
    __shared__ int seg[256][33];   // +1 pad vs bank conflicts
    const int n = blockIdx.x * 256 + threadIdx.x;
    if (n >= NN) return;
    const int s0 = start[n], s1 = start[n + 1];
    const int d = s1 - s0;
    if (d <= 32) {
        int* a = seg[threadIdx.x];
        for (int i = 0; i < d; i++) a[i] = perm[s0 + i];
        for (int i = 1; i < d; i++) {
            const int v = a[i];
            int j = i - 1;
            while (j >= 0 && a[j] > v) { a[j + 1] = a[j]; j--; }
            a[j + 1] = v;
        }
        for (int i = 0; i < d; i++) {
            const int eid = a[i];
            pairs[s0 + i] = make_int2(eid, src[eid]);
        }
    } else {
        for (int i = s0 + 1; i < s1; i++) {
            const int v = perm[i];
            int j = i - 1;
            while (j >= s0 && perm[j] > v) { perm[j + 1] = perm[j]; j--; }
            perm[j + 1] = v;
        }
        for (int i = s0; i < s1; i++) {
            const int eid = perm[i];
            pairs[i] = make_int2(eid, src[eid]);
        }
    }
}

// ---------- single-launch weight pack ----------
// per-matrix layout: idx = (((ct*KC+kc)*nsp+sp)*64 + lane)*8 + j
// value = part_sp(W[k][m]), k = kc*32+(lane>>4)*8+j (0 if k>=K), m = ct*16+(lane&15)
DEVFN void packone(const float* __restrict__ W, int K, int KC, int nsp,
                   int idx, ushort* __restrict__ out)
{
    const int j = idx & 7, lane = (idx >> 3) & 63;
    const int sp = (idx >> 9) % nsp;
    const int rest = (idx >> 9) / nsp;
    const int kc = rest % KC;
    const int ct = rest / KC;
    const int k = kc * 32 + (lane >> 4) * 8 + j;
    const int m = ct * 16 + (lane & 15);
    const float w = (k < K) ? W[(size_t)k * H + m] : 0.f;
    const ushort hh = f2bf(w);
    out[idx] = (sp == 0) ? hh : f2bf(w - bftof(hh));
}

constexpr int SZ_W1 = 8 * 2 * 512;           // plain, KC=2
constexpr int SZ_W2 = 8 * 4 * 512;           // plain, KC=4
constexpr int SZ_WN = 8 * 3 * 2 * 512;       // split, KC=3
constexpr int SZ_WC = 8 * 4 * 2 * 512;       // split, KC=4 (per layer)

__global__ void k_packall(const float* __restrict__ We1, const float* __restrict__ We2,
                          const float* __restrict__ Wn, const float* __restrict__ Wc,
                          ushort* __restrict__ w1p, ushort* __restrict__ w2p,
                          ushort* __restrict__ wnp, ushort* __restrict__ wcp)
{
    int idx = blockIdx.x * 256 + threadIdx.x;
    if (idx < SZ_W1) { packone(We1, FE, 2, 1, idx, w1p); return; }
    idx -= SZ_W1;
    if (idx < SZ_W2) { packone(We2, H, 4, 1, idx, w2p); return; }
    idx -= SZ_W2;
    if (idx < SZ_WN) { packone(Wn, FN, 3, 2, idx, wnp); return; }
    idx -= SZ_WN;
    if (idx < 3 * SZ_WC) {
        const int l = idx / SZ_WC;
        packone(Wc + (size_t)l * H * H, H, 4, 2, idx - l * SZ_WC, wcp + (size_t)l * SZ_WC);
    }
}
constexpr int PACK_TOT = SZ_W1 + SZ_W2 + SZ_WN + 3 * SZ_WC;

// ---------- node embedding: h = x @ Wn + bn (split x split, ~exact), bf16 out ----------
__global__ __launch_bounds__(256, 4) void k_node_embed(
    const float* __restrict__ X, const ushort* __restrict__ wp,
    const float* __restrict__ bias, ushort* __restrict__ hb, int nrows)
{
    constexpr int KC = 3, K = FN, WV = 48;   // 4B words staged per row
    __shared__ unsigned hi_s[64 * 64];   // 16KB: [row][256B], swizzled
    __shared__ unsigned lo_s[64 * 64];   // 16KB
    const int tid = threadIdx.x;
    const int r0 = blockIdx.x * 64;

    for (int i = tid; i < 64 * WV; i += 256) {
        const int row = i / WV, w = i - row * WV;
        const int gr = min(r0 + row, nrows - 1);
        const int k = w * 2;
        unsigned hw = 0, lw = 0;
        if (k < K) {
            const float vx = X[(size_t)gr * K + k];
            const float vy = (k + 1 < K) ? X[(size_t)gr * K + k + 1] : 0.f;
            const ushort hx = f2bf(vx), hy = f2bf(vy);
            hw = (unsigned)hx | ((unsigned)hy << 16);
            lw = (unsigned)f2bf(vx - bftof(hx)) | ((unsigned)f2bf(vy - bftof(hy)) << 16);
        }
        const int a = (row * 256 + ((w * 4) ^ ((row & 7) << 4))) >> 2;
        hi_s[a] = hw; lo_s[a] = lw;
    }
    __syncthreads();

    const int wid = tid >> 6, lane = tid & 63;
    const int q = lane >> 4, e = lane & 15;
    const int row = wid * 16 + e;
    const short8v* wf = (const short8v*)wp;

    f32x4 acc[8];
#pragma unroll
    for (int ct = 0; ct < 8; ct++) acc[ct] = (f32x4)0.f;

#pragma unroll
    for (int kc = 0; kc < KC; kc++) {
        const int off = row * 256 + ((kc * 64 + q * 16) ^ ((row & 7) << 4));
        const short8v bh = *(const short8v*)((const char*)hi_s + off);
        const short8v bl = *(const short8v*)((const char*)lo_s + off);
#pragma unroll
        for (int ct = 0; ct < 8; ct++) {
            const short8v a_h = wf[((ct * KC + kc) * 2 + 0) * 64 + lane];
            const short8v a_l = wf[((ct * KC + kc) * 2 + 1) * 64 + lane];
            acc[ct] = __builtin_amdgcn_mfma_f32_16x16x32_bf16(a_h, bh, acc[ct], 0, 0, 0);
            acc[ct] = __builtin_amdgcn_mfma_f32_16x16x32_bf16(a_h, bl, acc[ct], 0, 0, 0);
            acc[ct] = __builtin_amdgcn_mfma_f32_16x16x32_bf16(a_l, bh, acc[ct], 0, 0, 0);
        }
    }

    const int node = r0 + row;
    if (node < nrows) {
#pragma unroll
        for (int ct = 0; ct < 8; ct++) {
            const int col = ct * 16 + q * 4;
            const float4 bb = *(const float4*)&bias[col];
            ushort4 ub;
            ub.x = f2bf(acc[ct][0] + bb.x);
            ub.y = f2bf(acc[ct][1] + bb.y);
            ub.z = f2bf(acc[ct][2] + bb.z);
            ub.w = f2bf(acc[ct][3] + bb.w);
            *(ushort4*)&hb[(size_t)node * H + col] = ub;
        }
    }
}

// ---------- layer transform: t = h @ Wc (split-W x bf16-h, 2-term), bf16 out ----------
__global__ __launch_bounds__(256, 4) void k_node_xform(
    const ushort* __restrict__ hb, const ushort* __restrict__ wp,
    ushort* __restrict__ tb, int nrows)
{
    __shared__ unsigned b_s[64 * 64];   // 16KB: [row][256B], swizzled
    const int tid = threadIdx.x;
    const int r0 = blockIdx.x * 64;

    for (int i = tid; i < 64 * 64; i += 256) {
        const int row = i >> 6, w = i & 63;
        const int gr = min(r0 + row, nrows - 1);
        const unsigned hw = ((const unsigned*)&hb[(size_t)gr * H])[w];
        b_s[(row * 256 + ((w * 4) ^ ((row & 7) << 4))) >> 2] = hw;
    }
    __syncthreads();

    const int wid = tid >> 6, lane = tid & 63;
    const int q = lane >> 4, e = lane & 15;
    const int row = wid * 16 + e;
    const short8v* wf = (const short8v*)wp;

    f32x4 acc[8];
#pragma unroll
    for (int ct = 0; ct < 8; ct++) acc[ct] = (f32x4)0.f;

#pragma unroll
    for (int kc = 0; kc < 4; kc++) {
        const int off = row * 256 + ((kc * 64 + q * 16) ^ ((row & 7) << 4));
        const short8v b = *(const short8v*)((const char*)b_s + off);
#pragma unroll
        for (int ct = 0; ct < 8; ct++) {
            const short8v a_h = wf[((ct * 4 + kc) * 2 + 0) * 64 + lane];
            const short8v a_l = wf[((ct * 4 + kc) * 2 + 1) * 64 + lane];
            acc[ct] = __builtin_amdgcn_mfma_f32_16x16x32_bf16(a_h, b, acc[ct], 0, 0, 0);
            acc[ct] = __builtin_amdgcn_mfma_f32_16x16x32_bf16(a_l, b, acc[ct], 0, 0, 0);
        }
    }

    const int node = r0 + row;
    if (node < nrows) {
#pragma unroll
        for (int ct = 0; ct < 8; ct++) {
            const int col = ct * 16 + q * 4;
            ushort4 ub;
            ub.x = f2bf(acc[ct][0]);
            ub.y = f2bf(acc[ct][1]);
            ub.z = f2bf(acc[ct][2]);
            ub.w = f2bf(acc[ct][3]);
            *(ushort4*)&tb[(size_t)node * H + col] = ub;
        }
    }
}

// ---------- MFMA edge MLP: original order, plain-bf16 weights, sequential ----------
__global__ __launch_bounds__(256, 4) void k_edge_mfma(
    const float* __restrict__ attr, const int* __restrict__ src,
    const int* __restrict__ dst, const float* __restrict__ dis,
    const ushort* __restrict__ w1p, const ushort* __restrict__ w2p,
    const float* __restrict__ b1, const float* __restrict__ b2,
    ushort* __restrict__ eout)
{
    __shared__ unsigned ah_s[TE * 32];    // attr bf16 [row][128B], swizzled, 16KB
    __shared__ unsigned tmp_s[TE * 32];   // tmp  bf16 [row][128B], swizzled, 16KB
    __shared__ float nrm_s[TE];
    const int tid = threadIdx.x;
    const int e0 = blockIdx.x * TE;

    if (tid < TE) {
        const int ee = min(e0 + tid, NE - 1);
        nrm_s[tid] = dis[src[ee]] * dis[dst[ee]];
    }
    for (int i = tid; i < TE * 32; i += 256) {
        const int row = i >> 5, w = i & 31;
        unsigned hw = 0;
        if (w < 25) {
            const int ee = min(e0 + row, NE - 1);
            const float2 v = *(const float2*)&attr[(size_t)ee * FE + w * 2];
            hw = (unsigned)f2bf(v.x) | ((unsigned)f2bf(v.y) << 16);
        }
        ah_s[(row * 128 + ((w * 4) ^ ((row & 7) << 4))) >> 2] = hw;
    }
    __syncthreads();

    const int wid = tid >> 6, lane = tid & 63;
    const int q = lane >> 4, e = lane & 15;
    const int rowA = (wid * 2 + 0) * 16 + e;
    const int rowB = (wid * 2 + 1) * 16 + e;
    const short8v* w1f = (const short8v*)w1p;
    const short8v* w2f = (const short8v*)w2p;

    f32x4 acc2[8][2];
#pragma unroll
    for (int ct = 0; ct < 8; ct++)
#pragma unroll
        for (int et = 0; et < 2; et++) acc2[ct][et] = (f32x4)0.f;

#pragma unroll
    for (int p = 0; p < 2; p++) {
        // ---- GEMM1: tmp cols [p*64, p*64+64) ----
        f32x4 acc1[4][2];
#pragma unroll
        for (int c = 0; c < 4; c++)
#pragma unroll
            for (int et = 0; et < 2; et++) acc1[c][et] = (f32x4)0.f;

#pragma unroll
        for (int kc = 0; kc < 2; kc++) {
            const short8v bA = *(const short8v*)((const char*)ah_s +
                rowA * 128 + ((kc * 64 + q * 16) ^ ((rowA & 7) << 4)));
            const short8v bB = *(const short8v*)((const char*)ah_s +
                rowB * 128 + ((kc * 64 + q * 16) ^ ((rowB & 7) << 4)));
            short8v a1r[4];
#pragma unroll
            for (int c = 0; c < 4; c++)
                a1r[c] = w1f[((p * 4 + c) * 2 + kc) * 64 + lane];
#pragma unroll
            for (int c = 0; c < 4; c++) {
                acc1[c][0] = __builtin_amdgcn_mfma_f32_16x16x32_bf16(a1r[c], bA, acc1[c][0], 0, 0, 0);
                acc1[c][1] = __builtin_amdgcn_mfma_f32_16x16x32_bf16(a1r[c], bB, acc1[c][1], 0, 0, 0);
            }
        }

        if (p == 1) __syncthreads();   // all GEMM2(p=0) tmp reads done before overwrite

        // ---- bias + relu + bf16 pack -> tmp LDS ----
#pragma unroll
        for (int c = 0; c < 4; c++) {
            const int ct = p * 4 + c;
            const float4 b1v = *(const float4*)&b1[ct * 16 + q * 4];
#pragma unroll
            for (int et = 0; et < 2; et++) {
                const int row = (wid * 2 + et) * 16 + e;
                const float v0 = fmaxf(acc1[c][et][0] + b1v.x, 0.f);
                const float v1 = fmaxf(acc1[c][et][1] + b1v.y, 0.f);
                const float v2 = fmaxf(acc1[c][et][2] + b1v.z, 0.f);
                const float v3 = fmaxf(acc1[c][et][3] + b1v.w, 0.f);
                unsigned* dptr = &tmp_s[(row * 128 + ((c * 32 + q * 8) ^ ((row & 7) << 4))) >> 2];
                dptr[0] = (unsigned)f2bf(v0) | ((unsigned)f2bf(v1) << 16);
                dptr[1] = (unsigned)f2bf(v2) | ((unsigned)f2bf(v3) << 16);
            }
        }
        __syncthreads();

        // ---- GEMM2: kc2 = 2p, 2p+1 ----
#pragma unroll
        for (int kk = 0; kk < 2; kk++) {
            const int kc2 = p * 2 + kk;
            const short8v tA = *(const short8v*)((const char*)tmp_s +
                rowA * 128 + ((kk * 64 + q * 16) ^ ((rowA & 7) << 4)));
            const short8v tB = *(const short8v*)((const char*)tmp_s +
                rowB * 128 + ((kk * 64 + q * 16) ^ ((rowB & 7) << 4)));
            short8v a2r[8];
#pragma unroll
            for (int ct2 = 0; ct2 < 8; ct2++)
                a2r[ct2] = w2f[(ct2 * 4 + kc2) * 64 + lane];
#pragma unroll
            for (int ct2 = 0; ct2 < 8; ct2++) {
                acc2[ct2][0] = __builtin_amdgcn_mfma_f32_16x16x32_bf16(a2r[ct2], tA, acc2[ct2][0], 0, 0, 0);
                acc2[ct2][1] = __builtin_amdgcn_mfma_f32_16x16x32_bf16(a2r[ct2], tB, acc2[ct2][1], 0, 0, 0);
            }
        }
    }

    // ---- epilogue: (acc2+b2)*nrm -> bf16, direct sequential stores ----
#pragma unroll
    for (int ct2 = 0; ct2 < 8; ct2++) {
        const float4 b2v = *(const float4*)&b2[ct2 * 16 + q * 4];
#pragma unroll
        for (int et = 0; et < 2; et++) {
            const int row = (wid * 2 + et) * 16 + e;
            const int ee = e0 + row;
            if (ee < NE) {
                const float nm = nrm_s[row];
                ushort4 ov;
                ov.x = f2bf((acc2[ct2][et][0] + b2v.x) * nm);
                ov.y = f2bf((acc2[ct2][et][1] + b2v.y) * nm);
                ov.z = f2bf((acc2[ct2][et][2] + b2v.z) * nm);
                ov.w = f2bf((acc2[ct2][et][3] + b2v.w) * nm);
                *(ushort4*)&eout[(size_t)ee * H + ct2 * 16 + q * 4] = ov;
            }
        }
    }
}

// ---------- CSR aggregate + self-loop + bias + relu, fused; bf16 h out ----------
// 4 nodes per wave, 16 lanes per node; pairs look-ahead prefetch
__global__ void k_agg(const ushort* __restrict__ tbf, const ushort* __restrict__ ebuf,
                      const int2* __restrict__ pairs, const int* __restrict__ start,
                      const float* __restrict__ dis, const float* __restrict__ bias,
                      ushort* __restrict__ hb)
{
    const int wv = (blockIdx.x * blockDim.x + threadIdx.x) >> 6;
    const int lane = threadIdx.x & 63;
    const int node = wv * 4 + (lane >> 4);
    if (node >= NN) return;
    const int f0 = (lane & 15) * 8;
    const int s0 = start[node], s1 = start[node + 1];

    float a0[8], a1[8];
#pragma unroll
    for (int i = 0; i < 8; i++) { a0[i] = 0.f; a1[i] = 0.f; }

    int slot = s0;
    int2 pA = pairs[min(slot, NE - 1)];
    int2 pB = pairs[min(slot + 1, NE - 1)];
    for (; slot + 2 <= s1; ) {
        const int2 cA = pA, cB = pB;
        pA = pairs[min(slot + 2, NE - 1)];
        pB = pairs[min(slot + 3, NE - 1)];
        const uint4 eA = *(const uint4*)&ebuf[(size_t)cA.x * H + f0];
        const uint4 tA = *(const uint4*)&tbf[(size_t)cA.y * H + f0];
        const uint4 eB = *(const uint4*)&ebuf[(size_t)cB.x * H + f0];
        const uint4 tB = *(const uint4*)&tbf[(size_t)cB.y * H + f0];
        const unsigned ea[4] = {eA.x, eA.y, eA.z, eA.w};
        const unsigned ta[4] = {tA.x, tA.y, tA.z, tA.w};
        const unsigned eb[4] = {eB.x, eB.y, eB.z, eB.w};
        const unsigned tb[4] = {tB.x, tB.y, tB.z, tB.w};
#pragma unroll
        for (int w = 0; w < 4; w++) {
            a0[2 * w]     = fmaf(bflo(ta[w]), bflo(ea[w]), a0[2 * w]);
            a0[2 * w + 1] = fmaf(bfhi(ta[w]), bfhi(ea[w]), a0[2 * w + 1]);
            a1[2 * w]     = fmaf(bflo(tb[w]), bflo(eb[w]), a1[2 * w]);
            a1[2 * w + 1] = fmaf(bfhi(tb[w]), bfhi(eb[w]), a1[2 * w + 1]);
        }
        slot += 2;
    }
    if (slot < s1) {
        const uint4 eA = *(const uint4*)&ebuf[(size_t)pA.x * H + f0];
        const uint4 tA = *(const uint4*)&tbf[(size_t)pA.y * H + f0];
        const unsigned ea[4] = {eA.x, eA.y, eA.z, eA.w};
        const unsigned ta[4] = {tA.x, tA.y, tA.z, tA.w};
#pragma unroll
        for (int w = 0; w < 4; w++) {
            a0[2 * w]     = fmaf(bflo(ta[w]), bflo(ea[w]), a0[2 * w]);
            a0[2 * w + 1] = fmaf(bfhi(ta[w]), bfhi(ea[w]), a0[2 * w + 1]);
        }
    }

    const float ds = dis[node];
    const float d2 = ds * ds;
    const uint4 tsv = *(const uint4*)&tbf[(size_t)node * H + f0];
    const unsigned ts[4] = {tsv.x, tsv.y, tsv.z, tsv.w};
    const float4 bb0 = *(const float4*)&bias[f0];
    const float4 bb1 = *(const float4*)&bias[f0 + 4];
    const float bb[8] = {bb0.x, bb0.y, bb0.z, bb0.w, bb1.x, bb1.y, bb1.z, bb1.w};
    ushort r[8];
#pragma unroll
    for (int w = 0; w < 4; w++) {
        r[2 * w]     = f2bf(fmaxf(a0[2 * w]     + a1[2 * w]     + bflo(ts[w]) * d2 + bb[2 * w],     0.f));
        r[2 * w + 1] = f2bf(fmaxf(a0[2 * w + 1] + a1[2 * w + 1] + bfhi(ts[w]) * d2 + bb[2 * w + 1], 0.f));
    }
    ushort4 o0 = {r[0], r[1], r[2], r[3]};
    ushort4 o1 = {r[4], r[5], r[6], r[7]};
    *(ushort4*)&hb[(size_t)node * H + f0]     = o0;
    *(ushort4*)&hb[(size_t)node * H + f0 + 4] = o1;
}

// ---------- fused mean-pool + head (bf16 h input, inline graph bounds) ----------
DEVFN int lbound(const int* __restrict__ batch, int g)
{
    int lo = 0, hi = NN;
    while (lo < hi) {
        const int mid = (lo + hi) >> 1;
        if (batch[mid] < g) lo = mid + 1; else hi = mid;
    }
    return lo;
}

__global__ void k_pool_head(const ushort* __restrict__ hb, const int* __restrict__ batch,
                            const float* __restrict__ W1, const float* __restrict__ b1,
                            const float* __restrict__ W2, const float* __restrict__ b2,
                            float* __restrict__ out)
{
    __shared__ float gs[H];
    __shared__ float red[2];
    const int gi = blockIdx.x;
    const int f = threadIdx.x;
    const int n0 = lbound(batch, gi);
    const int n1 = lbound(batch, gi + 1);
    float sum = 0.f;
    for (int n = n0; n < n1; n++) sum += bftof(hb[(size_t)n * H + f]);
    const float cnt = fmaxf((float)(n1 - n0), 1.0f);
    gs[f] = sum / cnt;
    __syncthreads();
    float acc = b1[f];
#pragma unroll 4
    for (int k = 0; k < H; k++) acc = fmaf(gs[k], W1[k * H + f], acc);
    float v = fmaxf(acc, 0.f) * W2[f];
#pragma unroll
    for (int off = 32; off > 0; off >>= 1) v += __shfl_down(v, off, 64);
    if ((f & 63) == 0) red[f >> 6] = v;
    __syncthreads();
    if (f == 0) out[gi] = red[0] + red[1] + b2[0];
}

extern "C" void kernel_launch(void* const* d_in, const int* in_sizes, int n_in,
                              void* d_out, int out_size, void* d_ws, size_t ws_size,
                              hipStream_t stream)
{
    const float* x    = (const float*)d_in[0];
    const float* attr = (const float*)d_in[1];
    const int*   ei   = (const int*)d_in[2];
    const int*   bat  = (const int*)d_in[3];
    const float* Wn   = (const float*)d_in[4];
    const float* bn   = (const float*)d_in[5];
    const float* We1  = (const float*)d_in[6];
    const float* be1  = (const float*)d_in[7];
    const float* We2  = (const float*)d_in[8];
    const float* be2  = (const float*)d_in[9];
    const float* Wc   = (const float*)d_in[10];
    const float* bc   = (const float*)d_in[11];
    const float* Wl1  = (const float*)d_in[12];
    const float* bl1  = (const float*)d_in[13];
    const float* Wl2  = (const float*)d_in[14];
    const float* bl2  = (const float*)d_in[15];
    float* out = (float*)d_out;
    const int* src = ei;
    const int* dst = ei + NE;

    auto aln = [](size_t v) { return (v + 255) & ~(size_t)255; };
    char* p = (char*)d_ws;
    auto carve = [&](size_t bytes) { char* r = p; p += aln(bytes); return r; };
    ushort* hb      = (ushort*)carve((size_t)NN * H * 2);
    ushort* tbf     = (ushort*)carve((size_t)NN * H * 2);
    int*    deg     = (int*)  carve((size_t)NN * 4);
    int*    startC  = (int*)  carve((size_t)(NN + 1) * 4);
    int*    cursor  = (int*)  carve((size_t)NN * 4);
    float*  dis     = (float*)carve((size_t)NN * 4);
    int*    perm    = (int*)  carve((size_t)NE * 4);
    int2*   pairs   = (int2*) carve((size_t)NE * 8);
    ushort* w1p     = (ushort*)carve((size_t)SZ_W1 * 2);
    ushort* w2p     = (ushort*)carve((size_t)SZ_W2 * 2);
    ushort* wnp     = (ushort*)carve((size_t)SZ_WN * 2);
    ushort* wcp     = (ushort*)carve((size_t)3 * SZ_WC * 2);
    ushort* ebuf    = (ushort*)carve((size_t)NE * H * 2);

    // CSR build (deterministic); single memset covers deg..cursor span
    const size_t zspan = (size_t)((char*)cursor - (char*)deg) + (size_t)NN * 4;
    hipMemsetAsync(deg, 0, zspan, stream);
    k_deg<<<(NE + 255) / 256, 256, 0, stream>>>(dst, deg);
    k_scan<<<1, 1024, 0, stream>>>(deg, startC, dis);
    k_place<<<(NE + 255) / 256, 256, 0, stream>>>(dst, startC, cursor, perm);
    k_sortseg<<<(NN + 255) / 256, 256, 0, stream>>>(startC, perm, src, pairs);

    // all weight packing in one launch
    k_packall<<<(PACK_TOT + 255) / 256, 256, 0, stream>>>(We1, We2, Wn, Wc,
                                                          w1p, w2p, wnp, wcp);

    // node embedding (split x split, ~exact), bf16 h out
    k_node_embed<<<(NN + 63) / 64, 256, 0, stream>>>(x, wnp, bn, hb, NN);

    // edge MLP (MFMA, original order, sequential store, norm folded)
    k_edge_mfma<<<NBLK_E, 256, 0, stream>>>(attr, src, dst, dis,
                                            w1p, w2p, be1, be2, ebuf);

    // GCN layers
    for (int l = 0; l < NL; l++) {
        k_node_xform<<<(NN + 63) / 64, 256, 0, stream>>>(
            hb, wcp + (size_t)l * SZ_WC, tbf, NN);
        k_agg<<<((NN + 3) / 4 * 64 + 255) / 256, 256, 0, stream>>>(
            tbf, ebuf, pairs, startC, dis, bc + (size_t)l * H, hb);
    }

    // fused pool + head (inline bounds)
    k_pool_head<<<NG, H, 0, stream>>>(hb, bat, Wl1, bl1, Wl2, bl2, out);
}